// Round 3
// baseline (138.106 us; speedup 1.0000x reference)
//
#include <hip/hip_runtime.h>
#include <hip/hip_bf16.h>

#define NTOK  (512 * 2048)        // 1,048,576 tokens
#define OUTC  11
#define NELEM (NTOK * OUTC)       // 11,534,336 fp32 output elements
#define NF4   (NELEM / 4)         // 2,883,584 float4 stores (exact, no tail)

static __device__ __forceinline__ float swishf(float v) { return v / (1.0f + expf(-v)); }

// ---------------- Kernel 1: build the 256x11 fp32 output lookup table ----------------
// One block, 256 threads; thread c computes the full forward pass for token id c.
// All float inputs are FP32; output is FP32 (reference returns float32).
__global__ __launch_bounds__(256) void build_table_k(
    const float* __restrict__ emb,
    const float* __restrict__ W112, const float* __restrict__ b112,
    const float* __restrict__ W113, const float* __restrict__ b113,
    const float* __restrict__ W115, const float* __restrict__ b115,
    const float* __restrict__ W117, const float* __restrict__ b117,
    const float* __restrict__ W21,  const float* __restrict__ b21,
    const float* __restrict__ W31,  const float* __restrict__ b31,
    const float* __restrict__ W51,  const float* __restrict__ b51,
    const float* __restrict__ W71,  const float* __restrict__ b71,
    const float* __restrict__ W111, const float* __restrict__ b111,
    const float* __restrict__ Wout, const float* __restrict__ bout,
    float* __restrict__ table)   // 256*11 fp32
{
    __shared__ float sW[73 * 11];
    __shared__ float sb[11];
    for (int i = threadIdx.x; i < 73 * 11; i += 256) sW[i] = Wout[i];
    if (threadIdx.x < 11) sb[threadIdx.x] = bout[threadIdx.x];
    __syncthreads();

    const int c = threadIdx.x;  // token id 0..255

    float x[11];
    #pragma unroll
    for (int k = 0; k < 11; ++k) x[k] = emb[c * 11 + k];

    float d112[2];
    #pragma unroll
    for (int j = 0; j < 2; ++j) {
        float a = b112[j];
        #pragma unroll
        for (int k = 0; k < 11; ++k) a += x[k] * W112[k * 2 + j];
        d112[j] = swishf(a);
    }
    float d113[3];
    #pragma unroll
    for (int j = 0; j < 3; ++j) {
        float a = b113[j];
        #pragma unroll
        for (int k = 0; k < 11; ++k) a += x[k] * W113[k * 3 + j];
        d113[j] = swishf(a);
    }
    float d115[5];
    #pragma unroll
    for (int j = 0; j < 5; ++j) {
        float a = b115[j];
        #pragma unroll
        for (int k = 0; k < 11; ++k) a += x[k] * W115[k * 5 + j];
        d115[j] = swishf(a);
    }
    float d117[7];
    #pragma unroll
    for (int j = 0; j < 7; ++j) {
        float a = b117[j];
        #pragma unroll
        for (int k = 0; k < 11; ++k) a += x[k] * W117[k * 7 + j];
        d117[j] = swishf(a);
    }

    float s[5];
    {
        float a = b21[0] + d112[0] * W21[0] + d112[1] * W21[1];
        s[0] = swishf(a);
    }
    {
        float a = b31[0];
        #pragma unroll
        for (int j = 0; j < 3; ++j) a += d113[j] * W31[j];
        s[1] = swishf(a);
    }
    {
        float a = b51[0];
        #pragma unroll
        for (int j = 0; j < 5; ++j) a += d115[j] * W51[j];
        s[2] = swishf(a);
    }
    {
        float a = b71[0];
        #pragma unroll
        for (int j = 0; j < 7; ++j) a += d117[j] * W71[j];
        s[3] = swishf(a);
    }
    {
        float a = b111[0];
        #pragma unroll
        for (int k = 0; k < 11; ++k) a += x[k] * W111[k];
        s[4] = swishf(a);
    }

    float cat[73];
    int idx = 0;
    #pragma unroll
    for (int k = 0; k < 11; ++k) cat[idx++] = x[k];
    #pragma unroll
    for (int j = 0; j < 2; ++j) cat[idx++] = d112[j];
    #pragma unroll
    for (int j = 0; j < 3; ++j) cat[idx++] = d113[j];
    #pragma unroll
    for (int j = 0; j < 5; ++j) cat[idx++] = d115[j];
    #pragma unroll
    for (int j = 0; j < 7; ++j) cat[idx++] = d117[j];
    #pragma unroll
    for (int i = 0; i < 5; ++i) cat[idx++] = s[i];

    const int PI[10] = {0, 0, 0, 0, 1, 1, 1, 2, 2, 3};
    const int PJ[10] = {1, 2, 3, 4, 2, 3, 4, 3, 4, 4};
    #pragma unroll
    for (int p = 0; p < 10; ++p) cat[idx++] = s[PI[p]] + s[PJ[p]];
    #pragma unroll
    for (int p = 0; p < 10; ++p) cat[idx++] = s[PI[p]] * s[PJ[p]];
    #pragma unroll
    for (int p = 0; p < 10; ++p) cat[idx++] = fminf(s[PI[p]], s[PJ[p]]);
    #pragma unroll
    for (int p = 0; p < 10; ++p) cat[idx++] = fmaxf(s[PI[p]], s[PJ[p]]);

    for (int o = 0; o < 11; ++o) {
        float a = sb[o];
        #pragma unroll
        for (int i = 0; i < 73; ++i) a += cat[i] * sW[i * 11 + o];
        table[c * 11 + o] = tanhf(a);
    }
}

// ---------------- Kernel 2: gather table rows into the fp32 output ----------------
// Each thread produces one aligned float4 = 4 fp32 output elements. A window of
// 4 elements spans at most 2 consecutive tokens (row length 11 >= 4).
__global__ __launch_bounds__(256) void gather_k(
    const int* __restrict__ tokens,
    const float* __restrict__ table_g,
    float4* __restrict__ out)
{
    __shared__ float tbl[256 * 11];  // 11264 B
    const int tid = threadIdx.x;
    #pragma unroll
    for (int i = tid; i < 256 * 11; i += 256) tbl[i] = table_g[i];
    __syncthreads();

    const unsigned int q  = blockIdx.x * 256u + tid;   // float4 index
    const unsigned int e0 = q * 4u;                    // first element index
    const unsigned int t0 = e0 / 11u;                  // magic-mul div
    const unsigned int r0 = e0 - t0 * 11u;
    unsigned int t1 = t0 + 1u;
    if (t1 >= (unsigned int)NTOK) t1 = NTOK - 1u;      // clamp (only hit when no cross)

    const unsigned int base0 = (unsigned int)tokens[t0] * 11u;
    const unsigned int base1 = (unsigned int)tokens[t1] * 11u;

    float v[4];
    #pragma unroll
    for (int j = 0; j < 4; ++j) {
        const unsigned int r = r0 + (unsigned int)j;
        const bool second = (r >= 11u);
        const unsigned int idx = second ? (base1 + r - 11u) : (base0 + r);
        v[j] = tbl[idx];
    }

    out[q] = make_float4(v[0], v[1], v[2], v[3]);
}

extern "C" void kernel_launch(void* const* d_in, const int* in_sizes, int n_in,
                              void* d_out, int out_size, void* d_ws, size_t ws_size,
                              hipStream_t stream)
{
    const int* tokens = (const int*)d_in[0];
    #define FP(i) ((const float*)d_in[i])
    float* table = (float*)d_ws;  // 11264 B scratch

    build_table_k<<<1, 256, 0, stream>>>(
        FP(1),
        FP(2),  FP(3),  FP(4),  FP(5),
        FP(6),  FP(7),  FP(8),  FP(9),
        FP(10), FP(11), FP(12), FP(13),
        FP(14), FP(15), FP(16), FP(17),
        FP(18), FP(19), FP(20), FP(21),
        table);

    gather_k<<<NF4 / 256, 256, 0, stream>>>(
        tokens, (const float*)d_ws, (float4*)d_out);
    #undef FP
}

// Round 4
// 134.268 us; speedup vs baseline: 1.0286x; 1.0286x over previous
//
#include <hip/hip_runtime.h>
#include <hip/hip_bf16.h>

#define NTOK  (512 * 2048)        // 1,048,576 tokens
#define OUTC  11
#define NELEM (NTOK * OUTC)       // 11,534,336 fp32 output elements
#define NF4   (NELEM / 4)         // 2,883,584 float4 stores (exact, no tail)
#define GBLK  1408                // gather blocks; 1408*256*8 == NF4 exactly
#define GSTEP (GBLK * 256u)       // 360,448 float4 per grid sweep

static __device__ __forceinline__ float swishf(float v) { return v / (1.0f + expf(-v)); }

// ---------------- Kernel 1: build the 256x11 fp32 output lookup table ----------------
// One block, 256 threads; thread c computes the full forward pass for token id c.
// Wout/bout are read with thread-uniform indices -> compiler emits scalar loads
// (no LDS staging needed; removes 803 ds_read_b32 per thread vs round 3).
__global__ __launch_bounds__(256) void build_table_k(
    const float* __restrict__ emb,
    const float* __restrict__ W112, const float* __restrict__ b112,
    const float* __restrict__ W113, const float* __restrict__ b113,
    const float* __restrict__ W115, const float* __restrict__ b115,
    const float* __restrict__ W117, const float* __restrict__ b117,
    const float* __restrict__ W21,  const float* __restrict__ b21,
    const float* __restrict__ W31,  const float* __restrict__ b31,
    const float* __restrict__ W51,  const float* __restrict__ b51,
    const float* __restrict__ W71,  const float* __restrict__ b71,
    const float* __restrict__ W111, const float* __restrict__ b111,
    const float* __restrict__ Wout, const float* __restrict__ bout,
    float* __restrict__ table)   // 256*11 fp32
{
    const int c = threadIdx.x;  // token id 0..255

    float x[11];
    #pragma unroll
    for (int k = 0; k < 11; ++k) x[k] = emb[c * 11 + k];

    float d112[2];
    #pragma unroll
    for (int j = 0; j < 2; ++j) {
        float a = b112[j];
        #pragma unroll
        for (int k = 0; k < 11; ++k) a += x[k] * W112[k * 2 + j];
        d112[j] = swishf(a);
    }
    float d113[3];
    #pragma unroll
    for (int j = 0; j < 3; ++j) {
        float a = b113[j];
        #pragma unroll
        for (int k = 0; k < 11; ++k) a += x[k] * W113[k * 3 + j];
        d113[j] = swishf(a);
    }
    float d115[5];
    #pragma unroll
    for (int j = 0; j < 5; ++j) {
        float a = b115[j];
        #pragma unroll
        for (int k = 0; k < 11; ++k) a += x[k] * W115[k * 5 + j];
        d115[j] = swishf(a);
    }
    float d117[7];
    #pragma unroll
    for (int j = 0; j < 7; ++j) {
        float a = b117[j];
        #pragma unroll
        for (int k = 0; k < 11; ++k) a += x[k] * W117[k * 7 + j];
        d117[j] = swishf(a);
    }

    float s[5];
    {
        float a = b21[0] + d112[0] * W21[0] + d112[1] * W21[1];
        s[0] = swishf(a);
    }
    {
        float a = b31[0];
        #pragma unroll
        for (int j = 0; j < 3; ++j) a += d113[j] * W31[j];
        s[1] = swishf(a);
    }
    {
        float a = b51[0];
        #pragma unroll
        for (int j = 0; j < 5; ++j) a += d115[j] * W51[j];
        s[2] = swishf(a);
    }
    {
        float a = b71[0];
        #pragma unroll
        for (int j = 0; j < 7; ++j) a += d117[j] * W71[j];
        s[3] = swishf(a);
    }
    {
        float a = b111[0];
        #pragma unroll
        for (int k = 0; k < 11; ++k) a += x[k] * W111[k];
        s[4] = swishf(a);
    }

    float cat[73];
    int idx = 0;
    #pragma unroll
    for (int k = 0; k < 11; ++k) cat[idx++] = x[k];
    #pragma unroll
    for (int j = 0; j < 2; ++j) cat[idx++] = d112[j];
    #pragma unroll
    for (int j = 0; j < 3; ++j) cat[idx++] = d113[j];
    #pragma unroll
    for (int j = 0; j < 5; ++j) cat[idx++] = d115[j];
    #pragma unroll
    for (int j = 0; j < 7; ++j) cat[idx++] = d117[j];
    #pragma unroll
    for (int i = 0; i < 5; ++i) cat[idx++] = s[i];

    const int PI[10] = {0, 0, 0, 0, 1, 1, 1, 2, 2, 3};
    const int PJ[10] = {1, 2, 3, 4, 2, 3, 4, 3, 4, 4};
    #pragma unroll
    for (int p = 0; p < 10; ++p) cat[idx++] = s[PI[p]] + s[PJ[p]];
    #pragma unroll
    for (int p = 0; p < 10; ++p) cat[idx++] = s[PI[p]] * s[PJ[p]];
    #pragma unroll
    for (int p = 0; p < 10; ++p) cat[idx++] = fminf(s[PI[p]], s[PJ[p]]);
    #pragma unroll
    for (int p = 0; p < 10; ++p) cat[idx++] = fmaxf(s[PI[p]], s[PJ[p]]);

    for (int o = 0; o < 11; ++o) {
        float a = bout[o];                      // uniform -> scalar load
        #pragma unroll
        for (int i = 0; i < 73; ++i) a += cat[i] * Wout[i * 11 + o];  // uniform -> scalar
        table[c * 11 + o] = tanhf(a);
    }
}

// ---------------- Kernel 2: gather table rows into the fp32 output ----------------
// Grid-stride: each thread produces 8 aligned float4 (4 fp32 each). A window of
// 4 elements spans at most 2 consecutive tokens (row length 11 >= 4).
__global__ __launch_bounds__(256) void gather_k(
    const int* __restrict__ tokens,
    const float* __restrict__ table_g,
    float4* __restrict__ out)
{
    __shared__ float tbl[256 * 11];  // 11264 B, stride 11 (odd) -> benign banking
    const int tid = threadIdx.x;
    #pragma unroll
    for (int i = tid; i < 256 * 11; i += 256) tbl[i] = table_g[i];
    __syncthreads();

    unsigned int q = blockIdx.x * 256u + (unsigned int)tid;   // float4 index
    #pragma unroll
    for (int k = 0; k < 8; ++k, q += GSTEP) {
        const unsigned int e0 = q * 4u;                // first element index
        const unsigned int t0 = e0 / 11u;              // magic-mul div
        const unsigned int r0 = e0 - t0 * 11u;
        unsigned int t1 = t0 + 1u;
        if (t1 >= (unsigned int)NTOK) t1 = NTOK - 1u;  // clamp (only when no cross)

        const unsigned int base0 = (unsigned int)tokens[t0] * 11u;
        const unsigned int base1 = (unsigned int)tokens[t1] * 11u;

        float v[4];
        #pragma unroll
        for (int j = 0; j < 4; ++j) {
            const unsigned int r = r0 + (unsigned int)j;
            const bool second = (r >= 11u);
            const unsigned int idx = second ? (base1 + r - 11u) : (base0 + r);
            v[j] = tbl[idx];
        }

        out[q] = make_float4(v[0], v[1], v[2], v[3]);
    }
}

extern "C" void kernel_launch(void* const* d_in, const int* in_sizes, int n_in,
                              void* d_out, int out_size, void* d_ws, size_t ws_size,
                              hipStream_t stream)
{
    const int* tokens = (const int*)d_in[0];
    #define FP(i) ((const float*)d_in[i])
    float* table = (float*)d_ws;  // 11264 B scratch

    build_table_k<<<1, 256, 0, stream>>>(
        FP(1),
        FP(2),  FP(3),  FP(4),  FP(5),
        FP(6),  FP(7),  FP(8),  FP(9),
        FP(10), FP(11), FP(12), FP(13),
        FP(14), FP(15), FP(16), FP(17),
        FP(18), FP(19), FP(20), FP(21),
        table);

    gather_k<<<GBLK, 256, 0, stream>>>(
        tokens, (const float*)d_ws, (float4*)d_out);
    #undef FP
}

// Round 6
// 132.586 us; speedup vs baseline: 1.0416x; 1.0127x over previous
//
#include <hip/hip_runtime.h>
#include <hip/hip_bf16.h>

#define NTOK  (512 * 2048)        // 1,048,576 tokens
#define OUTC  11
#define NELEM (NTOK * OUTC)       // 11,534,336 fp32 output elements
#define NF4   (NELEM / 4)         // 2,883,584 float4 stores (exact)
#define GBLK  512                 // 512*256*22 == NF4 exactly (2 blocks/CU)
#define GITER 22
#define GSTEP (GBLK * 256u)       // 131,072 float4 per grid sweep

typedef float v4f __attribute__((ext_vector_type(4)));  // native vector: OK for nontemporal builtin

static __device__ __forceinline__ float swishf(float v) { return v / (1.0f + expf(-v)); }

// Single fused kernel: every block rebuilds the 256x11 fp32 token->output table
// in its own LDS (~1 us of VALU, overlapped across the 2 resident blocks/CU),
// then streams the gathered output with nontemporal float4 stores.
__global__ __launch_bounds__(256) void fused_k(
    const int* __restrict__ tokens,
    const float* __restrict__ emb,
    const float* __restrict__ W112, const float* __restrict__ b112,
    const float* __restrict__ W113, const float* __restrict__ b113,
    const float* __restrict__ W115, const float* __restrict__ b115,
    const float* __restrict__ W117, const float* __restrict__ b117,
    const float* __restrict__ W21,  const float* __restrict__ b21,
    const float* __restrict__ W31,  const float* __restrict__ b31,
    const float* __restrict__ W51,  const float* __restrict__ b51,
    const float* __restrict__ W71,  const float* __restrict__ b71,
    const float* __restrict__ W111, const float* __restrict__ b111,
    const float* __restrict__ Wout, const float* __restrict__ bout,
    v4f* __restrict__ out)
{
    __shared__ float tbl[256 * 11];  // 11264 B, stride 11 (odd) -> benign banking
    const int tid = threadIdx.x;

    // ---------------- Phase 1: build table row `tid` ----------------
    {
        const int c = tid;  // token id 0..255

        float x[11];
        #pragma unroll
        for (int k = 0; k < 11; ++k) x[k] = emb[c * 11 + k];

        float d112[2];
        #pragma unroll
        for (int j = 0; j < 2; ++j) {
            float a = b112[j];
            #pragma unroll
            for (int k = 0; k < 11; ++k) a += x[k] * W112[k * 2 + j];
            d112[j] = swishf(a);
        }
        float d113[3];
        #pragma unroll
        for (int j = 0; j < 3; ++j) {
            float a = b113[j];
            #pragma unroll
            for (int k = 0; k < 11; ++k) a += x[k] * W113[k * 3 + j];
            d113[j] = swishf(a);
        }
        float d115[5];
        #pragma unroll
        for (int j = 0; j < 5; ++j) {
            float a = b115[j];
            #pragma unroll
            for (int k = 0; k < 11; ++k) a += x[k] * W115[k * 5 + j];
            d115[j] = swishf(a);
        }
        float d117[7];
        #pragma unroll
        for (int j = 0; j < 7; ++j) {
            float a = b117[j];
            #pragma unroll
            for (int k = 0; k < 11; ++k) a += x[k] * W117[k * 7 + j];
            d117[j] = swishf(a);
        }

        float s[5];
        {
            float a = b21[0] + d112[0] * W21[0] + d112[1] * W21[1];
            s[0] = swishf(a);
        }
        {
            float a = b31[0];
            #pragma unroll
            for (int j = 0; j < 3; ++j) a += d113[j] * W31[j];
            s[1] = swishf(a);
        }
        {
            float a = b51[0];
            #pragma unroll
            for (int j = 0; j < 5; ++j) a += d115[j] * W51[j];
            s[2] = swishf(a);
        }
        {
            float a = b71[0];
            #pragma unroll
            for (int j = 0; j < 7; ++j) a += d117[j] * W71[j];
            s[3] = swishf(a);
        }
        {
            float a = b111[0];
            #pragma unroll
            for (int k = 0; k < 11; ++k) a += x[k] * W111[k];
            s[4] = swishf(a);
        }

        float cat[73];
        int idx = 0;
        #pragma unroll
        for (int k = 0; k < 11; ++k) cat[idx++] = x[k];
        #pragma unroll
        for (int j = 0; j < 2; ++j) cat[idx++] = d112[j];
        #pragma unroll
        for (int j = 0; j < 3; ++j) cat[idx++] = d113[j];
        #pragma unroll
        for (int j = 0; j < 5; ++j) cat[idx++] = d115[j];
        #pragma unroll
        for (int j = 0; j < 7; ++j) cat[idx++] = d117[j];
        #pragma unroll
        for (int i = 0; i < 5; ++i) cat[idx++] = s[i];

        const int PI[10] = {0, 0, 0, 0, 1, 1, 1, 2, 2, 3};
        const int PJ[10] = {1, 2, 3, 4, 2, 3, 4, 3, 4, 4};
        #pragma unroll
        for (int p = 0; p < 10; ++p) cat[idx++] = s[PI[p]] + s[PJ[p]];
        #pragma unroll
        for (int p = 0; p < 10; ++p) cat[idx++] = s[PI[p]] * s[PJ[p]];
        #pragma unroll
        for (int p = 0; p < 10; ++p) cat[idx++] = fminf(s[PI[p]], s[PJ[p]]);
        #pragma unroll
        for (int p = 0; p < 10; ++p) cat[idx++] = fmaxf(s[PI[p]], s[PJ[p]]);

        for (int o = 0; o < 11; ++o) {
            float a = bout[o];                              // uniform -> scalar load
            #pragma unroll
            for (int i = 0; i < 73; ++i) a += cat[i] * Wout[i * 11 + o];
            tbl[c * 11 + o] = tanhf(a);
        }
    }
    __syncthreads();

    // ---------------- Phase 2: gather, 22 float4 per thread ----------------
    unsigned int q = blockIdx.x * 256u + (unsigned int)tid;   // float4 index
    for (int k = 0; k < GITER; ++k, q += GSTEP) {
        const unsigned int e0 = q * 4u;                // first element index
        const unsigned int t0 = e0 / 11u;              // magic-mul div
        const unsigned int r0 = e0 - t0 * 11u;
        unsigned int t1 = t0 + 1u;
        if (t1 >= (unsigned int)NTOK) t1 = NTOK - 1u;  // clamp (only when no cross)

        const unsigned int base0 = (unsigned int)tokens[t0] * 11u;
        const unsigned int base1 = (unsigned int)tokens[t1] * 11u;

        float v[4];
        #pragma unroll
        for (int j = 0; j < 4; ++j) {
            const unsigned int r = r0 + (unsigned int)j;
            const bool second = (r >= 11u);
            const unsigned int idx = second ? (base1 + r - 11u) : (base0 + r);
            v[j] = tbl[idx];
        }

        v4f o;
        o.x = v[0]; o.y = v[1]; o.z = v[2]; o.w = v[3];
        __builtin_nontemporal_store(o, &out[q]);
    }
}

extern "C" void kernel_launch(void* const* d_in, const int* in_sizes, int n_in,
                              void* d_out, int out_size, void* d_ws, size_t ws_size,
                              hipStream_t stream)
{
    const int* tokens = (const int*)d_in[0];
    #define FP(i) ((const float*)d_in[i])

    fused_k<<<GBLK, 256, 0, stream>>>(
        tokens,
        FP(1),
        FP(2),  FP(3),  FP(4),  FP(5),
        FP(6),  FP(7),  FP(8),  FP(9),
        FP(10), FP(11), FP(12), FP(13),
        FP(14), FP(15), FP(16), FP(17),
        FP(18), FP(19), FP(20), FP(21),
        (v4f*)d_out);
    #undef FP
}